// Round 6
// baseline (116.490 us; speedup 1.0000x reference)
//
#include <hip/hip_runtime.h>

#define NCH 30
#define TILE_CELLS 128
#define TILE_FLOATS (TILE_CELLS * NCH)     // 3840 floats per array per tile
#define TILE_F4     (TILE_FLOATS / 4)      // 960 float4
#define GRID_MAIN 512

__global__ void __launch_bounds__(256) yolo_loss_main(
    const float* __restrict__ pred,
    const float* __restrict__ targ,
    float* __restrict__ partial,   // [GRID_MAIN][4]
    int ncells)
{
    __shared__ float lp[TILE_FLOATS];   // 15360 B
    __shared__ float lt[TILE_FLOATS];   // 15360 B
    __shared__ float red[4][4];

    const int tid  = threadIdx.x;
    const int lane = tid & 63;
    const int wv   = tid >> 6;

    const int ntiles = ncells / TILE_CELLS;          // 3136
    const int grid   = gridDim.x;                    // 512
    const int q = ntiles / grid, r = ntiles % grid;
    const int myn     = q + (blockIdx.x < r ? 1 : 0);          // 6 or 7 tiles
    const int mystart = blockIdx.x * q + min((int)blockIdx.x, r);

    const float4* p4 = (const float4*)pred;
    const float4* t4 = (const float4*)targ;
    float4* lp4 = (float4*)lp;
    float4* lt4 = (float4*)lt;

    float s_xywh = 0.f, s_obj = 0.f, s_noobj = 0.f, s_cls = 0.f;

    // staging registers (the "second buffer")
    float4 rp0, rp1, rp2, rp3, rt0, rt1, rt2, rt3;
    const bool has4 = (tid < TILE_F4 - 768);   // tid < 192: owns a 4th chunk

    // ---- prologue: load tile 0 into regs, write to LDS ----
    {
        size_t b4 = (size_t)mystart * TILE_F4;
        rp0 = p4[b4 + tid];        rt0 = t4[b4 + tid];
        rp1 = p4[b4 + tid + 256];  rt1 = t4[b4 + tid + 256];
        rp2 = p4[b4 + tid + 512];  rt2 = t4[b4 + tid + 512];
        if (has4) { rp3 = p4[b4 + tid + 768]; rt3 = t4[b4 + tid + 768]; }
        lp4[tid]       = rp0;  lt4[tid]       = rt0;
        lp4[tid + 256] = rp1;  lt4[tid + 256] = rt1;
        lp4[tid + 512] = rp2;  lt4[tid + 512] = rt2;
        if (has4) { lp4[tid + 768] = rp3; lt4[tid + 768] = rt3; }
    }
    __syncthreads();

    for (int it = 0; it < myn; ++it) {
        // ---- issue next tile's global loads (regs), before compute ----
        const bool more = (it + 1 < myn);
        if (more) {
            size_t b4 = (size_t)(mystart + it + 1) * TILE_F4;
            rp0 = p4[b4 + tid];        rt0 = t4[b4 + tid];
            rp1 = p4[b4 + tid + 256];  rt1 = t4[b4 + tid + 256];
            rp2 = p4[b4 + tid + 512];  rt2 = t4[b4 + tid + 512];
            if (has4) { rp3 = p4[b4 + tid + 768]; rt3 = t4[b4 + tid + 768]; }
        }

        // ---- compute current tile from LDS (threads 0..127) ----
        if (tid < TILE_CELLS) {
            const float2* P2 = (const float2*)(lp + tid * NCH);
            const float2* T2 = (const float2*)(lt + tid * NCH);

            float2 pA = P2[0], pB = P2[1], pC = P2[2], pD = P2[3], pE = P2[4];
            // p0..p9 = pA.x pA.y pB.x pB.y pC.x | pC.y pD.x pD.y pE.x pE.y
            float2 tA = T2[0], tB = T2[1];
            float  t4v = lt[tid * NCH + 4];
            float  t9v = lt[tid * NCH + 9];

            float coord = (t4v > 0.f)  ? 1.f : 0.f;
            float noobj = (t4v == 0.f) ? 1.f : 0.f;

            float tcx = tA.x / 7.0f, tcy = tA.y / 7.0f;
            float tx0 = tcx - 0.5f * tB.x, ty0 = tcy - 0.5f * tB.y;
            float tx1 = tcx + 0.5f * tB.x, ty1 = tcy + 0.5f * tB.y;
            float area_t = (tx1 - tx0) * (ty1 - ty0);

            float iou0, iou1;
            {   // box 0: p0,p1,p2,p3 = pA.x pA.y pB.x pB.y
                float cx = pA.x / 7.0f, cy = pA.y / 7.0f;
                float x0 = cx - 0.5f * pB.x, y0 = cy - 0.5f * pB.y;
                float x1 = cx + 0.5f * pB.x, y1 = cy + 0.5f * pB.y;
                float lx = fmaxf(x0, tx0), ly = fmaxf(y0, ty0);
                float rx = fminf(x1, tx1), ry = fminf(y1, ty1);
                float w = fmaxf(rx - lx, 0.f), h = fmaxf(ry - ly, 0.f);
                float inter = w * h;
                float area_p = (x1 - x0) * (y1 - y0);
                iou0 = inter / (area_p + area_t - inter);
            }
            {   // box 1: p5,p6,p7,p8 = pC.y pD.x pD.y pE.x
                float cx = pC.y / 7.0f, cy = pD.x / 7.0f;
                float x0 = cx - 0.5f * pD.y, y0 = cy - 0.5f * pE.x;
                float x1 = cx + 0.5f * pD.y, y1 = cy + 0.5f * pE.x;
                float lx = fmaxf(x0, tx0), ly = fmaxf(y0, ty0);
                float rx = fminf(x1, tx1), ry = fminf(y1, ty1);
                float w = fmaxf(rx - lx, 0.f), h = fmaxf(ry - ly, 0.f);
                float inter = w * h;
                float area_p = (x1 - x0) * (y1 - y0);
                iou1 = inter / (area_p + area_t - inter);
            }
            int best = (iou1 > iou0) ? 1 : 0;      // argmax tie -> box 0
            float max_iou = fmaxf(iou0, iou1);

            float rx_ = best ? pC.y : pA.x;
            float ry_ = best ? pD.x : pA.y;
            float rw_ = best ? pD.y : pB.x;
            float rh_ = best ? pE.x : pB.y;
            float rc_ = best ? pE.y : pC.x;

            float dx = rx_ - tA.x, dy = ry_ - tA.y;
            float dw = sqrtf(rw_) - sqrtf(tB.x);
            float dh = sqrtf(rh_) - sqrtf(tB.y);
            s_xywh += coord * (dx*dx + dy*dy + dw*dw + dh*dh);

            float dobj = rc_ - max_iou;
            s_obj += coord * dobj * dobj;

            float d4 = pC.x - t4v, d9 = pE.y - t9v;
            s_noobj += noobj * (d4*d4 + d9*d9);

            float cls = 0.f;
            #pragma unroll
            for (int i = 5; i < 15; ++i) {          // channels 10..29
                float2 pc = P2[i], tc = T2[i];
                float e0 = pc.x - tc.x, e1 = pc.y - tc.y;
                cls += e0*e0 + e1*e1;
            }
            s_cls += coord * cls;
        }

        __builtin_amdgcn_s_barrier();   // all LDS reads of tile `it` done

        if (more) {
            // regs for tile it+1 ready? wait own loads, then publish to LDS
            asm volatile("s_waitcnt vmcnt(0)" ::: "memory");
            lp4[tid]       = rp0;  lt4[tid]       = rt0;
            lp4[tid + 256] = rp1;  lt4[tid + 256] = rt1;
            lp4[tid + 512] = rp2;  lt4[tid + 512] = rt2;
            if (has4) { lp4[tid + 768] = rp3; lt4[tid + 768] = rt3; }
            __builtin_amdgcn_s_barrier();   // writes visible before next compute
        }
    }

    // ---- block reduction ----
    #pragma unroll
    for (int off = 32; off > 0; off >>= 1) {
        s_xywh  += __shfl_down(s_xywh, off);
        s_obj   += __shfl_down(s_obj, off);
        s_noobj += __shfl_down(s_noobj, off);
        s_cls   += __shfl_down(s_cls, off);
    }
    if (lane == 0) {
        red[wv][0] = s_xywh; red[wv][1] = s_obj;
        red[wv][2] = s_noobj; red[wv][3] = s_cls;
    }
    __syncthreads();
    if (tid == 0) {
        float a = 0.f, b = 0.f, c = 0.f, d = 0.f;
        #pragma unroll
        for (int w = 0; w < 4; ++w) {
            a += red[w][0]; b += red[w][1]; c += red[w][2]; d += red[w][3];
        }
        float4* out4 = (float4*)(partial + (size_t)blockIdx.x * 4);
        *out4 = make_float4(a, b, c, d);
    }
}

__global__ void __launch_bounds__(256) yolo_finalize(
    const float* __restrict__ partial, int nblocks,
    float* __restrict__ out, float inv_bs)
{
    int tid = threadIdx.x;
    float a = 0.f, b = 0.f, c = 0.f, d = 0.f;
    for (int r = tid; r < nblocks; r += 256) {
        const float4 v = *(const float4*)(partial + (size_t)r * 4);
        a += v.x; b += v.y; c += v.z; d += v.w;
    }
    #pragma unroll
    for (int off = 32; off > 0; off >>= 1) {
        a += __shfl_down(a, off);
        b += __shfl_down(b, off);
        c += __shfl_down(c, off);
        d += __shfl_down(d, off);
    }
    __shared__ float red[4][4];
    int wid = tid >> 6, lane = tid & 63;
    if (lane == 0) { red[wid][0]=a; red[wid][1]=b; red[wid][2]=c; red[wid][3]=d; }
    __syncthreads();
    if (tid == 0) {
        float xywh=0.f, obj=0.f, noobj=0.f, cls=0.f;
        #pragma unroll
        for (int w = 0; w < 4; ++w) {
            xywh += red[w][0]; obj += red[w][1];
            noobj += red[w][2]; cls += red[w][3];
        }
        out[0] = (5.0f * xywh + obj + 0.5f * noobj + cls) * inv_bs;
        out[1] = xywh;
        out[2] = obj;
        out[3] = noobj;
        out[4] = cls;
    }
}

extern "C" void kernel_launch(void* const* d_in, const int* in_sizes, int n_in,
                              void* d_out, int out_size, void* d_ws, size_t ws_size,
                              hipStream_t stream)
{
    const float* pred = (const float*)d_in[0];
    const float* targ = (const float*)d_in[1];
    float* out = (float*)d_out;
    float* partial = (float*)d_ws;

    int ncells = in_sizes[0] / NCH;          // 401408 = 3136 tiles of 128
    float inv_bs = 1.0f / (float)(ncells / 49);

    yolo_loss_main<<<GRID_MAIN, 256, 0, stream>>>(pred, targ, partial, ncells);
    yolo_finalize<<<1, 256, 0, stream>>>(partial, GRID_MAIN, out, inv_bs);
}

// Round 9
// 115.265 us; speedup vs baseline: 1.0106x; 1.0106x over previous
//
#include <hip/hip_runtime.h>

#define NCH 30
#define TILE_CELLS 128
#define TILE_FLOATS (TILE_CELLS * NCH)   // 3840 floats = 15 chunks of 256
#define GRID_MAIN 512                    // 2 blocks/CU -> all co-resident
#define SENT 0x5AFE5AFEu

typedef __attribute__((address_space(3))) unsigned int lds_u32_t;
typedef __attribute__((address_space(1))) unsigned int glb_u32_t;

// Issue one tile's global->LDS DMA. 30 combined chunks (15 pred + 15 targ),
// chunk c: array = c&1, chunk index = c>>1. Wave w takes c = w, w+4, ...
// -> waves 0,1 issue 8 loads; waves 2,3 issue 7.
__device__ __forceinline__ void issue_tile(
    const float* __restrict__ pred, const float* __restrict__ targ,
    float* ldsP, float* ldsT, size_t tileBase, int wv, int lane)
{
    #pragma unroll
    for (int c = 0; c < 30; ++c) {
        if ((c & 3) == wv) {
            const int ci = c >> 1;
            const float* g = ((c & 1) ? targ : pred) + tileBase + ci * 256 + lane * 4;
            float* l = ((c & 1) ? ldsT : ldsP) + ci * 256;
            __builtin_amdgcn_global_load_lds((const glb_u32_t*)g, (lds_u32_t*)l, 16, 0, 0);
        }
    }
}

__global__ void __launch_bounds__(256) yolo_loss_main(
    const float* __restrict__ pred,
    const float* __restrict__ targ,
    float* __restrict__ partial,        // ws: [GRID_MAIN][4] floats
    unsigned* __restrict__ flags,       // ws: [GRID_MAIN] sentinels
    float* __restrict__ out, float inv_bs,
    int ncells)
{
    __shared__ float bufP[2][TILE_FLOATS];   // 2 x 15360 B
    __shared__ float bufT[2][TILE_FLOATS];   // 2 x 15360 B
    __shared__ float red[4][4];

    const int tid  = threadIdx.x;
    const int lane = tid & 63;
    const int wv   = tid >> 6;
    const int ntiles = ncells / TILE_CELLS;  // 3136
    const int stride = gridDim.x;            // 512

    float s_xywh = 0.f, s_obj = 0.f, s_noobj = 0.f, s_cls = 0.f;

    int t = blockIdx.x;
    issue_tile(pred, targ, bufP[0], bufT[0], (size_t)t * TILE_FLOATS, wv, lane);

    int cur = 0;
    for (; t < ntiles; t += stride) {
        int nt = t + stride;
        if (nt < ntiles) {
            issue_tile(pred, targ, bufP[cur ^ 1], bufT[cur ^ 1],
                       (size_t)nt * TILE_FLOATS, wv, lane);
            // own outstanding = next tile's loads -> current tile complete
            if (wv < 2) asm volatile("s_waitcnt vmcnt(8)" ::: "memory");
            else        asm volatile("s_waitcnt vmcnt(7)" ::: "memory");
        } else {
            asm volatile("s_waitcnt vmcnt(0)" ::: "memory");
        }
        __builtin_amdgcn_s_barrier();   // raw barrier: do NOT drain vmcnt

        if (tid < TILE_CELLS) {
            const float2* cp2 = (const float2*)(bufP[cur] + tid * NCH);
            const float2* ct2 = (const float2*)(bufT[cur] + tid * NCH);
            float pv[NCH], tv[NCH];
            #pragma unroll
            for (int i = 0; i < 15; ++i) {
                float2 a = cp2[i]; pv[2*i] = a.x; pv[2*i+1] = a.y;
                float2 b = ct2[i]; tv[2*i] = b.x; tv[2*i+1] = b.y;
            }
            float conf_t = tv[4];
            float coord = (conf_t > 0.f)  ? 1.f : 0.f;
            float noobj = (conf_t == 0.f) ? 1.f : 0.f;

            float tcx = tv[0] / 7.0f, tcy = tv[1] / 7.0f;
            float tx0 = tcx - 0.5f * tv[2], ty0 = tcy - 0.5f * tv[3];
            float tx1 = tcx + 0.5f * tv[2], ty1 = tcy + 0.5f * tv[3];
            float area_t = (tx1 - tx0) * (ty1 - ty0);

            float iou[2];
            #pragma unroll
            for (int b = 0; b < 2; ++b) {
                const float* pb = pv + 5 * b;
                float cx = pb[0] / 7.0f, cy = pb[1] / 7.0f;
                float x0 = cx - 0.5f * pb[2], y0 = cy - 0.5f * pb[3];
                float x1 = cx + 0.5f * pb[2], y1 = cy + 0.5f * pb[3];
                float lx = fmaxf(x0, tx0), ly = fmaxf(y0, ty0);
                float rx = fminf(x1, tx1), ry = fminf(y1, ty1);
                float w = fmaxf(rx - lx, 0.f), h = fmaxf(ry - ly, 0.f);
                float inter = w * h;
                float area_p = (x1 - x0) * (y1 - y0);
                iou[b] = inter / (area_p + area_t - inter);
            }
            int best = (iou[1] > iou[0]) ? 1 : 0;   // argmax ties -> box 0
            float max_iou = fmaxf(iou[0], iou[1]);
            const float* rp = pv + 5 * best;

            float dx = rp[0] - tv[0], dy = rp[1] - tv[1];
            float dw = sqrtf(rp[2]) - sqrtf(tv[2]);
            float dh = sqrtf(rp[3]) - sqrtf(tv[3]);
            s_xywh += coord * (dx*dx + dy*dy + dw*dw + dh*dh);

            float dobj = rp[4] - max_iou;
            s_obj += coord * dobj * dobj;

            float cls = 0.f;
            #pragma unroll
            for (int c = 10; c < 30; ++c) { float d = pv[c] - tv[c]; cls += d * d; }
            s_cls += coord * cls;

            float d4 = pv[4] - tv[4], d9 = pv[9] - tv[9];
            s_noobj += noobj * (d4*d4 + d9*d9);
        }
        __builtin_amdgcn_s_barrier();   // buffer free before next overwrite
        cur ^= 1;
    }

    // ---- per-block reduction ----
    #pragma unroll
    for (int off = 32; off > 0; off >>= 1) {
        s_xywh  += __shfl_down(s_xywh, off);
        s_obj   += __shfl_down(s_obj, off);
        s_noobj += __shfl_down(s_noobj, off);
        s_cls   += __shfl_down(s_cls, off);
    }
    if (lane == 0) {
        red[wv][0] = s_xywh; red[wv][1] = s_obj;
        red[wv][2] = s_noobj; red[wv][3] = s_cls;
    }
    __syncthreads();
    if (tid == 0) {
        float a = 0.f, b = 0.f, c = 0.f, d = 0.f;
        #pragma unroll
        for (int w = 0; w < 4; ++w) {
            a += red[w][0]; b += red[w][1]; c += red[w][2]; d += red[w][3];
        }
        float* slot = partial + (size_t)blockIdx.x * 4;
        __hip_atomic_store(slot + 0, a, __ATOMIC_RELAXED, __HIP_MEMORY_SCOPE_AGENT);
        __hip_atomic_store(slot + 1, b, __ATOMIC_RELAXED, __HIP_MEMORY_SCOPE_AGENT);
        __hip_atomic_store(slot + 2, c, __ATOMIC_RELAXED, __HIP_MEMORY_SCOPE_AGENT);
        __hip_atomic_store(slot + 3, d, __ATOMIC_RELAXED, __HIP_MEMORY_SCOPE_AGENT);
        __hip_atomic_store(flags + blockIdx.x, SENT, __ATOMIC_RELEASE, __HIP_MEMORY_SCOPE_AGENT);
    }

    // ---- fused finalize: block 0 waits for all partials, reduces, writes out ----
    if (blockIdx.x == 0) {
        float a = 0.f, b = 0.f, c = 0.f, d = 0.f;
        for (int s = tid; s < GRID_MAIN; s += 256) {
            while (__hip_atomic_load(flags + s, __ATOMIC_ACQUIRE,
                                     __HIP_MEMORY_SCOPE_AGENT) != SENT)
                __builtin_amdgcn_s_sleep(2);
            const float* slot = partial + (size_t)s * 4;
            a += __hip_atomic_load(slot + 0, __ATOMIC_RELAXED, __HIP_MEMORY_SCOPE_AGENT);
            b += __hip_atomic_load(slot + 1, __ATOMIC_RELAXED, __HIP_MEMORY_SCOPE_AGENT);
            c += __hip_atomic_load(slot + 2, __ATOMIC_RELAXED, __HIP_MEMORY_SCOPE_AGENT);
            d += __hip_atomic_load(slot + 3, __ATOMIC_RELAXED, __HIP_MEMORY_SCOPE_AGENT);
        }
        #pragma unroll
        for (int off = 32; off > 0; off >>= 1) {
            a += __shfl_down(a, off);
            b += __shfl_down(b, off);
            c += __shfl_down(c, off);
            d += __shfl_down(d, off);
        }
        __syncthreads();   // red[] reuse: per-block phase fully done
        if (lane == 0) { red[wv][0]=a; red[wv][1]=b; red[wv][2]=c; red[wv][3]=d; }
        __syncthreads();
        if (tid == 0) {
            float xywh=0.f, obj=0.f, noobj=0.f, cls=0.f;
            #pragma unroll
            for (int w = 0; w < 4; ++w) {
                xywh += red[w][0]; obj += red[w][1];
                noobj += red[w][2]; cls += red[w][3];
            }
            out[0] = (5.0f * xywh + obj + 0.5f * noobj + cls) * inv_bs;
            out[1] = xywh;
            out[2] = obj;
            out[3] = noobj;
            out[4] = cls;
        }
    }
}

extern "C" void kernel_launch(void* const* d_in, const int* in_sizes, int n_in,
                              void* d_out, int out_size, void* d_ws, size_t ws_size,
                              hipStream_t stream)
{
    const float* pred = (const float*)d_in[0];
    const float* targ = (const float*)d_in[1];
    float* out = (float*)d_out;
    float* partial = (float*)d_ws;                          // 512 * 16 B
    unsigned* flags = (unsigned*)((char*)d_ws + GRID_MAIN * 4 * sizeof(float));

    int ncells = in_sizes[0] / NCH;          // 401408 = 3136 tiles of 128
    float inv_bs = 1.0f / (float)(ncells / 49);

    yolo_loss_main<<<GRID_MAIN, 256, 0, stream>>>(pred, targ, partial, flags,
                                                  out, inv_bs, ncells);
}